// Round 14
// baseline (94.595 us; speedup 1.0000x reference)
//
#include <hip/hip_runtime.h>
#include <math.h>

static constexpr float AFWD = 0.999f;
static constexpr float EPS  = 1e-5f;

typedef float vfloat4 __attribute__((ext_vector_type(4)));

// ---------------- Pass 1: chunk-local sums, explicit depth-8 load pipeline ---
__global__ __launch_bounds__(256) void onlnorm_pass1(
    const float* __restrict__ x, float* __restrict__ Sv,
    float* __restrict__ T0v, float* __restrict__ Ev, int n, int L)
{
    const int chunk = blockIdx.y;
    const int col = (blockIdx.x * blockDim.x + threadIdx.x) * 4;
    if (col >= L) return;
    const float a = AFWD, b = 1.0f - AFWD, ab = AFWD * (1.0f - AFWD);
    const float* xp = x + (size_t)chunk * (size_t)n * L + col;

    float m0=0.f,m1=0.f,m2=0.f,m3=0.f;
    float t0=0.f,t1=0.f,t2=0.f,t3=0.f;
    float e0=0.f,e1=0.f,e2=0.f,e3=0.f;

    constexpr int PF = 8;

#define P1_STEP(xv)                                                   \
    do { float d;                                                     \
        d = (xv).x - m0; e0 += d; t0 = a*t0 + ab*d*d; m0 += b*d;      \
        d = (xv).y - m1; e1 += d; t1 = a*t1 + ab*d*d; m1 += b*d;      \
        d = (xv).z - m2; e2 += d; t2 = a*t2 + ab*d*d; m2 += b*d;      \
        d = (xv).w - m3; e3 += d; t3 = a*t3 + ab*d*d; m3 += b*d;      \
    } while (0)

    if ((n % PF) == 0 && n >= 2 * PF) {
        float4 buf[PF];
        #pragma unroll
        for (int j = 0; j < PF; ++j)
            buf[j] = *reinterpret_cast<const float4*>(xp + (size_t)j * L);
        for (int i0 = 0; i0 + PF < n; i0 += PF) {
            #pragma unroll
            for (int j = 0; j < PF; ++j) {
                const float4 xv = buf[j];
                buf[j] = *reinterpret_cast<const float4*>(xp + (size_t)(i0 + PF + j) * L);
                P1_STEP(xv);
            }
        }
        #pragma unroll
        for (int j = 0; j < PF; ++j) { const float4 xv = buf[j]; P1_STEP(xv); }
    } else {
        for (int i = 0; i < n; ++i) {
            const float4 xv = *reinterpret_cast<const float4*>(xp + (size_t)i * L);
            P1_STEP(xv);
        }
    }
#undef P1_STEP

    const size_t base = (size_t)chunk * L + col;
    *reinterpret_cast<float4*>(Sv  + base) = make_float4(m0,m1,m2,m3);
    *reinterpret_cast<float4*>(T0v + base) = make_float4(t0,t1,t2,t3);
    *reinterpret_cast<float4*>(Ev  + base) = make_float4(e0,e1,e2,e3);
}

// ---------------- Pass 2: per-column serial carry scan, BATCH=32 ------------
// C=64 -> 2 dependent batch-rounds. 64 blocks x 64 threads.
__global__ __launch_bounds__(64) void onlnorm_pass2(
    const float* __restrict__ Sv, const float* __restrict__ T0v,
    const float* __restrict__ Ev, const float* __restrict__ mu0,
    const float* __restrict__ var0, float* __restrict__ muin,
    float* __restrict__ varin, int C, int L, float A, float B, float W)
{
    const int col = blockIdx.x * blockDim.x + threadIdx.x;
    if (col >= L) return;
    float mu = mu0[col], var = var0[col];
    constexpr int BATCH = 32;
    float sb[BATCH], tb[BATCH], eb[BATCH];
    int c0 = 0;
    for (; c0 + BATCH <= C; c0 += BATCH) {
        #pragma unroll
        for (int j = 0; j < BATCH; ++j) {
            const size_t idx = (size_t)(c0 + j) * L + col;
            sb[j] = Sv[idx]; tb[j] = T0v[idx]; eb[j] = Ev[idx];
        }
        #pragma unroll
        for (int j = 0; j < BATCH; ++j) {
            const size_t idx = (size_t)(c0 + j) * L + col;
            muin[idx]  = mu;
            varin[idx] = var;
            var = A*var + tb[j] - 2.0f*B*mu*eb[j] + W*mu*mu;
            mu  = A*mu + sb[j];
        }
    }
    for (; c0 < C; ++c0) {
        const size_t idx = (size_t)c0 * L + col;
        muin[idx] = mu; varin[idx] = var;
        const float s = Sv[idx], t = T0v[idx], e = Ev[idx];
        var = A*var + t - 2.0f*B*mu*e + W*mu*mu;
        mu  = A*mu + s;
    }
}

// ---------------- Pass 3: replay with true carry, pipelined, nt-stores ------
__global__ __launch_bounds__(256) void onlnorm_pass3(
    const float* __restrict__ x, const float* __restrict__ muin,
    const float* __restrict__ varin, float* __restrict__ out, int n, int L)
{
    const int chunk = blockIdx.y;
    const int col = (blockIdx.x * blockDim.x + threadIdx.x) * 4;
    if (col >= L) return;
    const float a = AFWD, b = 1.0f - AFWD, ab = AFWD * (1.0f - AFWD);
    const size_t cbase = (size_t)chunk * L + col;
    const float4 muv  = *reinterpret_cast<const float4*>(muin  + cbase);
    const float4 varv = *reinterpret_cast<const float4*>(varin + cbase);
    float m0=muv.x, m1=muv.y, m2=muv.z, m3=muv.w;
    float v0=varv.x, v1=varv.y, v2=varv.z, v3=varv.w;
    const float* xp = x   + (size_t)chunk * (size_t)n * L + col;
    float*       op = out + (size_t)chunk * (size_t)n * L + col;

    constexpr int PF = 8;

#define P3_STEP(xv, row)                                                        \
    do { vfloat4 ov; float d;                                                   \
        d = (xv).x - m0; ov.x = d * rsqrtf(v0 + EPS); v0 = a*v0 + ab*d*d; m0 += b*d; \
        d = (xv).y - m1; ov.y = d * rsqrtf(v1 + EPS); v1 = a*v1 + ab*d*d; m1 += b*d; \
        d = (xv).z - m2; ov.z = d * rsqrtf(v2 + EPS); v2 = a*v2 + ab*d*d; m2 += b*d; \
        d = (xv).w - m3; ov.w = d * rsqrtf(v3 + EPS); v3 = a*v3 + ab*d*d; m3 += b*d; \
        __builtin_nontemporal_store(ov, reinterpret_cast<vfloat4*>(op + (size_t)(row) * L)); \
    } while (0)

    if ((n % PF) == 0 && n >= 2 * PF) {
        float4 buf[PF];
        #pragma unroll
        for (int j = 0; j < PF; ++j)
            buf[j] = *reinterpret_cast<const float4*>(xp + (size_t)j * L);
        for (int i0 = 0; i0 + PF < n; i0 += PF) {
            #pragma unroll
            for (int j = 0; j < PF; ++j) {
                const float4 xv = buf[j];
                buf[j] = *reinterpret_cast<const float4*>(xp + (size_t)(i0 + PF + j) * L);
                P3_STEP(xv, i0 + j);
            }
        }
        const int ie = n - PF;
        #pragma unroll
        for (int j = 0; j < PF; ++j) { const float4 xv = buf[j]; P3_STEP(xv, ie + j); }
    } else {
        for (int i = 0; i < n; ++i) {
            const float4 xv = *reinterpret_cast<const float4*>(xp + (size_t)i * L);
            P3_STEP(xv, i);
        }
    }
#undef P3_STEP
}

extern "C" void kernel_launch(void* const* d_in, const int* in_sizes, int n_in,
                              void* d_out, int out_size, void* d_ws, size_t ws_size,
                              hipStream_t stream) {
    const float* x    = (const float*)d_in[0];
    const float* mu0  = (const float*)d_in[1];
    const float* var0 = (const float*)d_in[2];
    float* out = (float*)d_out;

    const int L = in_sizes[1];          // 4096
    const int N = in_sizes[0] / L;      // 8192

    // C=64 (n=128): pass2 -> 2 batch-rounds; ws traffic halved again vs C=128.
    // Streaming grid = 256 blocks (1/CU), 8 MB in flight with PF=8.
    int C = 64;
    while (C > 1 && ((size_t)5 * (size_t)C * L * sizeof(float) > ws_size ||
                     (N % C) != 0 || ((N / C) % 8) != 0))
        C >>= 1;
    const int n = N / C;

    float* Sv    = (float*)d_ws;
    float* T0v   = Sv    + (size_t)C * L;
    float* Ev    = T0v   + (size_t)C * L;
    float* muin  = Ev    + (size_t)C * L;
    float* varin = muin  + (size_t)C * L;

    const double a  = (double)AFWD;
    const double An = pow(a, (double)n);
    const float A = (float)An;
    const float B = (float)(An * (1.0 - a));
    const float W = (float)(An * (1.0 - An));

    const dim3 blk(256);
    const dim3 g1((L / 4 + 255) / 256, C);

    onlnorm_pass1<<<g1, blk, 0, stream>>>(x, Sv, T0v, Ev, n, L);
    onlnorm_pass2<<<dim3((L + 63) / 64), dim3(64), 0, stream>>>(
        Sv, T0v, Ev, mu0, var0, muin, varin, C, L, A, B, W);
    onlnorm_pass3<<<g1, blk, 0, stream>>>(x, muin, varin, out, n, L);
}

// Round 15
// 78.276 us; speedup vs baseline: 1.2085x; 1.2085x over previous
//
#include <hip/hip_runtime.h>
#include <math.h>

static constexpr float AFWD = 0.999f;
static constexpr float EPS  = 1e-5f;

typedef float vfloat4 __attribute__((ext_vector_type(4)));

// ---------------- Pass 1: chunk-local sums, explicit depth-8 load pipeline ---
__global__ __launch_bounds__(256) void onlnorm_pass1(
    const float* __restrict__ x, float* __restrict__ Sv,
    float* __restrict__ T0v, float* __restrict__ Ev, int n, int L)
{
    const int chunk = blockIdx.y;
    const int col = (blockIdx.x * blockDim.x + threadIdx.x) * 4;
    if (col >= L) return;
    const float a = AFWD, b = 1.0f - AFWD, ab = AFWD * (1.0f - AFWD);
    const float* xp = x + (size_t)chunk * (size_t)n * L + col;

    float m0=0.f,m1=0.f,m2=0.f,m3=0.f;
    float t0=0.f,t1=0.f,t2=0.f,t3=0.f;
    float e0=0.f,e1=0.f,e2=0.f,e3=0.f;

    constexpr int PF = 8;

#define P1_STEP(xv)                                                   \
    do { float d;                                                     \
        d = (xv).x - m0; e0 += d; t0 = a*t0 + ab*d*d; m0 += b*d;      \
        d = (xv).y - m1; e1 += d; t1 = a*t1 + ab*d*d; m1 += b*d;      \
        d = (xv).z - m2; e2 += d; t2 = a*t2 + ab*d*d; m2 += b*d;      \
        d = (xv).w - m3; e3 += d; t3 = a*t3 + ab*d*d; m3 += b*d;      \
    } while (0)

    if ((n % PF) == 0 && n >= 2 * PF) {
        float4 buf[PF];
        #pragma unroll
        for (int j = 0; j < PF; ++j)
            buf[j] = *reinterpret_cast<const float4*>(xp + (size_t)j * L);
        for (int i0 = 0; i0 + PF < n; i0 += PF) {
            #pragma unroll
            for (int j = 0; j < PF; ++j) {
                const float4 xv = buf[j];
                buf[j] = *reinterpret_cast<const float4*>(xp + (size_t)(i0 + PF + j) * L);
                P1_STEP(xv);
            }
        }
        #pragma unroll
        for (int j = 0; j < PF; ++j) { const float4 xv = buf[j]; P1_STEP(xv); }
    } else {
        for (int i = 0; i < n; ++i) {
            const float4 xv = *reinterpret_cast<const float4*>(xp + (size_t)i * L);
            P1_STEP(xv);
        }
    }
#undef P1_STEP

    const size_t base = (size_t)chunk * L + col;
    *reinterpret_cast<float4*>(Sv  + base) = make_float4(m0,m1,m2,m3);
    *reinterpret_cast<float4*>(T0v + base) = make_float4(t0,t1,t2,t3);
    *reinterpret_cast<float4*>(Ev  + base) = make_float4(e0,e1,e2,e3);
}

// ---------------- Pass 2: per-column serial carry scan, BATCH=32 ------------
// C=128 -> 4 dependent batch-rounds. 64 blocks x 64 threads.
__global__ __launch_bounds__(64) void onlnorm_pass2(
    const float* __restrict__ Sv, const float* __restrict__ T0v,
    const float* __restrict__ Ev, const float* __restrict__ mu0,
    const float* __restrict__ var0, float* __restrict__ muin,
    float* __restrict__ varin, int C, int L, float A, float B, float W)
{
    const int col = blockIdx.x * blockDim.x + threadIdx.x;
    if (col >= L) return;
    float mu = mu0[col], var = var0[col];
    constexpr int BATCH = 32;
    float sb[BATCH], tb[BATCH], eb[BATCH];
    int c0 = 0;
    for (; c0 + BATCH <= C; c0 += BATCH) {
        #pragma unroll
        for (int j = 0; j < BATCH; ++j) {
            const size_t idx = (size_t)(c0 + j) * L + col;
            sb[j] = Sv[idx]; tb[j] = T0v[idx]; eb[j] = Ev[idx];
        }
        #pragma unroll
        for (int j = 0; j < BATCH; ++j) {
            const size_t idx = (size_t)(c0 + j) * L + col;
            muin[idx]  = mu;
            varin[idx] = var;
            var = A*var + tb[j] - 2.0f*B*mu*eb[j] + W*mu*mu;
            mu  = A*mu + sb[j];
        }
    }
    for (; c0 < C; ++c0) {
        const size_t idx = (size_t)c0 * L + col;
        muin[idx] = mu; varin[idx] = var;
        const float s = Sv[idx], t = T0v[idx], e = Ev[idx];
        var = A*var + t - 2.0f*B*mu*e + W*mu*mu;
        mu  = A*mu + s;
    }
}

// ---------------- Pass 3: replay with true carry, pipelined, nt-stores ------
__global__ __launch_bounds__(256) void onlnorm_pass3(
    const float* __restrict__ x, const float* __restrict__ muin,
    const float* __restrict__ varin, float* __restrict__ out, int n, int L)
{
    const int chunk = blockIdx.y;
    const int col = (blockIdx.x * blockDim.x + threadIdx.x) * 4;
    if (col >= L) return;
    const float a = AFWD, b = 1.0f - AFWD, ab = AFWD * (1.0f - AFWD);
    const size_t cbase = (size_t)chunk * L + col;
    const float4 muv  = *reinterpret_cast<const float4*>(muin  + cbase);
    const float4 varv = *reinterpret_cast<const float4*>(varin + cbase);
    float m0=muv.x, m1=muv.y, m2=muv.z, m3=muv.w;
    float v0=varv.x, v1=varv.y, v2=varv.z, v3=varv.w;
    const float* xp = x   + (size_t)chunk * (size_t)n * L + col;
    float*       op = out + (size_t)chunk * (size_t)n * L + col;

    constexpr int PF = 8;

#define P3_STEP(xv, row)                                                        \
    do { vfloat4 ov; float d;                                                   \
        d = (xv).x - m0; ov.x = d * rsqrtf(v0 + EPS); v0 = a*v0 + ab*d*d; m0 += b*d; \
        d = (xv).y - m1; ov.y = d * rsqrtf(v1 + EPS); v1 = a*v1 + ab*d*d; m1 += b*d; \
        d = (xv).z - m2; ov.z = d * rsqrtf(v2 + EPS); v2 = a*v2 + ab*d*d; m2 += b*d; \
        d = (xv).w - m3; ov.w = d * rsqrtf(v3 + EPS); v3 = a*v3 + ab*d*d; m3 += b*d; \
        __builtin_nontemporal_store(ov, reinterpret_cast<vfloat4*>(op + (size_t)(row) * L)); \
    } while (0)

    if ((n % PF) == 0 && n >= 2 * PF) {
        float4 buf[PF];
        #pragma unroll
        for (int j = 0; j < PF; ++j)
            buf[j] = *reinterpret_cast<const float4*>(xp + (size_t)j * L);
        for (int i0 = 0; i0 + PF < n; i0 += PF) {
            #pragma unroll
            for (int j = 0; j < PF; ++j) {
                const float4 xv = buf[j];
                buf[j] = *reinterpret_cast<const float4*>(xp + (size_t)(i0 + PF + j) * L);
                P3_STEP(xv, i0 + j);
            }
        }
        const int ie = n - PF;
        #pragma unroll
        for (int j = 0; j < PF; ++j) { const float4 xv = buf[j]; P3_STEP(xv, ie + j); }
    } else {
        for (int i = 0; i < n; ++i) {
            const float4 xv = *reinterpret_cast<const float4*>(xp + (size_t)i * L);
            P3_STEP(xv, i);
        }
    }
#undef P3_STEP
}

extern "C" void kernel_launch(void* const* d_in, const int* in_sizes, int n_in,
                              void* d_out, int out_size, void* d_ws, size_t ws_size,
                              hipStream_t stream) {
    const float* x    = (const float*)d_in[0];
    const float* mu0  = (const float*)d_in[1];
    const float* var0 = (const float*)d_in[2];
    float* out = (float*)d_out;

    const int L = in_sizes[1];          // 4096
    const int N = in_sizes[0] / L;      // 8192

    // C=128 (n=64): measured optimum of the C-sweep (512->103.9, 256->82.2,
    // 128->78.4, 64->94.6 us). 512 streaming blocks = 2/CU.
    int C = 128;
    while (C > 1 && ((size_t)5 * (size_t)C * L * sizeof(float) > ws_size ||
                     (N % C) != 0 || ((N / C) % 8) != 0))
        C >>= 1;
    const int n = N / C;

    float* Sv    = (float*)d_ws;
    float* T0v   = Sv    + (size_t)C * L;
    float* Ev    = T0v   + (size_t)C * L;
    float* muin  = Ev    + (size_t)C * L;
    float* varin = muin  + (size_t)C * L;

    const double a  = (double)AFWD;
    const double An = pow(a, (double)n);
    const float A = (float)An;
    const float B = (float)(An * (1.0 - a));
    const float W = (float)(An * (1.0 - An));

    const dim3 blk(256);
    const dim3 g1((L / 4 + 255) / 256, C);

    onlnorm_pass1<<<g1, blk, 0, stream>>>(x, Sv, T0v, Ev, n, L);
    onlnorm_pass2<<<dim3((L + 63) / 64), dim3(64), 0, stream>>>(
        Sv, T0v, Ev, mu0, var0, muin, varin, C, L, A, B, W);
    onlnorm_pass3<<<g1, blk, 0, stream>>>(x, muin, varin, out, n, L);
}